// Round 8
// baseline (324.358 us; speedup 1.0000x reference)
//
#include <hip/hip_runtime.h>

#define HIDDEN 1024
#define NTOK (8 * 2048)   // B*S = 16384 tokens
#define BM 256
#define BN 128
#define BK 32
#define NT (HIDDEN / BK)  // 32 K-tiles

typedef __attribute__((ext_vector_type(4))) float f32x4;
typedef __attribute__((ext_vector_type(8))) short bf16x8;
typedef __attribute__((ext_vector_type(4))) unsigned short u16x4;
typedef __attribute__((ext_vector_type(8))) unsigned short u16x8;

__device__ inline unsigned short f2b(float f) {
    unsigned int u = __float_as_uint(f);
    u += 0x7fffu + ((u >> 16) & 1u);   // round-to-nearest-even
    return (unsigned short)(u >> 16);
}
__device__ inline float b2f(unsigned short u) {
    return __uint_as_float(((unsigned int)u) << 16);
}

// ---------------- fp32 -> bf16 convert, all 4 arrays in one launch ----------
__global__ __launch_bounds__(256) void cvt_all(
    const float4* __restrict__ x1, const float4* __restrict__ wq,
    const float4* __restrict__ wk, const float4* __restrict__ wv,
    u16x4* __restrict__ dst) {
    const int NX = NTOK * HIDDEN / 4;
    const int NW = HIDDEN * HIDDEN / 4;
    const int total = NX + 3 * NW;
    const int stride = gridDim.x * blockDim.x;
    for (int i = blockIdx.x * blockDim.x + threadIdx.x; i < total; i += stride) {
        const float4* s; int o;
        if (i < NX)               { s = x1; o = i; }
        else if (i < NX + NW)     { s = wq; o = i - NX; }
        else if (i < NX + 2 * NW) { s = wk; o = i - NX - NW; }
        else                      { s = wv; o = i - NX - 2 * NW; }
        float4 x = s[o];
        u16x4 r;
        r[0] = f2b(x.x); r[1] = f2b(x.y); r[2] = f2b(x.z); r[3] = f2b(x.w);
        dst[i] = r;
    }
}

__device__ inline void mm32(f32x4 (&acc)[8][4], const bf16x8 (&a)[8],
                            const bf16x8 (&b)[4]) {
#pragma unroll
    for (int m = 0; m < 8; ++m)
#pragma unroll
        for (int n = 0; n < 4; ++n)
            acc[m][n] = __builtin_amdgcn_mfma_f32_16x16x32_bf16(
                a[m], b[n], acc[m][n], 0, 0, 0);
}

// ---------------- fused QKV GEMM: ZERO-LDS, direct global->VGPR -------------
// C = X (16384x1024) * W^T + bias ; 64 m-tiles x 24 n-tiles = 1536 blocks.
// 4 waves (2M x 2N) of 128x64. NO LDS, NO BARRIERS: both A and B fragments
// are contiguous 16B rows in global memory (A[tok][k], W[col][k]), so each
// K-tile's 12 operands are plain global_load_dwordx4 served by L1/L2
// (per-block K-tile working set 24 KB < 32 KB L1; panels L2-resident via
// XCD supertile map). Waves are fully decoupled -> DS/MFMA lockstep of the
// LDS variants (4x nulls at 2830 cyc/tile = DS+MFMA serialized) is gone;
// compiler emits counted vmcnt between the register ping-pong sets.
// Register budget: 128 acc + 96 frags (E/O) + misc ~ 235 < 256 (2 w/SIMD).
__global__ __launch_bounds__(256, 2) void qkv_gemm(
    const unsigned short* __restrict__ Xb,
    const unsigned short* __restrict__ Wb,
    const float* __restrict__ bqp, const float* __restrict__ bkp,
    const float* __restrict__ bvp,
    unsigned short* __restrict__ QKV) {
    const int tid = threadIdx.x;
    const int lane = tid & 63, wave = tid >> 6;
    const int wm = wave >> 1, wn = wave & 1;      // 2x2 wave grid, 128x64 each

    // 2D super-tile XCD map: 64 super-tiles of (4 mt x 6 nt) = 24 blocks.
    const int bid = blockIdx.x;
    const int xcd = bid & 7;
    const int i6 = bid >> 3;            // 0..191
    const int st = i6 / 24;             // 0..7
    const int w = i6 % 24;              // 0..23
    const int g = xcd * 8 + st;         // global super-tile 0..63
    const int mt = (g >> 2) * 4 + w / 6;    // 0..63
    const int nt = (g & 3) * 6 + w % 6;     // 0..23
    const int mat = nt >> 3;                // 0=q 1=k 2=v
    const int col0 = (nt & 7) * BN;
    const int row0 = mt * BM;

    const unsigned short* Ag = Xb + (size_t)row0 * HIDDEN;
    const unsigned short* Bg = Wb + (size_t)mat * (HIDDEN * HIDDEN)
                                  + (size_t)col0 * HIDDEN;
    const float* bias = (mat == 0) ? bqp : ((mat == 1) ? bkp : bvp);
    unsigned short* Out = QKV + (size_t)mat * ((size_t)NTOK * HIDDEN);

    const int fr = lane & 15;
    const int kq = lane >> 4;
    const int loff = fr * HIDDEN + kq * 8;   // per-lane element offset

    // wave-uniform row bases (SGPR pairs); loff stays the single VGPR offset
    const unsigned short* baseA[8];
    const unsigned short* baseB[4];
#pragma unroll
    for (int m = 0; m < 8; ++m)
        baseA[m] = Ag + (size_t)(wm * 128 + m * 16) * HIDDEN;
#pragma unroll
    for (int n = 0; n < 4; ++n)
        baseB[n] = Bg + (size_t)(wn * 64 + n * 16) * HIDDEN;

    // prologue: tile 0 -> E set
    bf16x8 aE[8], bE[4], aO[8], bO[4];
#pragma unroll
    for (int n = 0; n < 4; ++n) bE[n] = *(const bf16x8*)(baseB[n] + loff);
#pragma unroll
    for (int m = 0; m < 8; ++m) aE[m] = *(const bf16x8*)(baseA[m] + loff);

    f32x4 acc[8][4] = {};

    for (int jj = 0; jj < NT; jj += 2) {
        // load tile jj+1 -> O (in flight across mm of E)
#pragma unroll
        for (int n = 0; n < 4; ++n)
            bO[n] = *(const bf16x8*)(baseB[n] + loff + BK);
#pragma unroll
        for (int m = 0; m < 8; ++m)
            aO[m] = *(const bf16x8*)(baseA[m] + loff + BK);
        mm32(acc, aE, bE);
        // load tile jj+2 -> E (dead loads at jj=30 land in d_ws, DCE'd/unused)
#pragma unroll
        for (int n = 0; n < 4; ++n)
            bE[n] = *(const bf16x8*)(baseB[n] + loff + 2 * BK);
#pragma unroll
        for (int m = 0; m < 8; ++m)
            aE[m] = *(const bf16x8*)(baseA[m] + loff + 2 * BK);
        mm32(acc, aO, bO);
        // uniform pointer bump (SGPR adds)
#pragma unroll
        for (int m = 0; m < 8; ++m) baseA[m] += 2 * BK;
#pragma unroll
        for (int n = 0; n < 4; ++n) baseB[n] += 2 * BK;
    }

    // epilogue: bias add, bf16 store. C/D map: col=lane&15, row=(lane>>4)*4+jj
    const int fq = lane >> 4;
    float bvv[4];
#pragma unroll
    for (int n = 0; n < 4; ++n) bvv[n] = bias[col0 + wn * 64 + n * 16 + fr];
#pragma unroll
    for (int m = 0; m < 8; ++m) {
#pragma unroll
        for (int n = 0; n < 4; ++n) {
            const int colg = col0 + wn * 64 + n * 16 + fr;
#pragma unroll
            for (int jj = 0; jj < 4; ++jj) {
                const int rowg = row0 + wm * 128 + m * 16 + fq * 4 + jj;
                Out[(size_t)rowg * HIDDEN + colg] = f2b(acc[m][n][jj] + bvv[n]);
            }
        }
    }
}

// ---------------- per-token attention over the HEAD dim ----------------------
// one wave per token; lane = h*8+g computes score[h][g]; softmax over g.
__global__ __launch_bounds__(256) void attn_k(const unsigned short* __restrict__ QKV,
                                              float* __restrict__ out) {
    __shared__ unsigned short sQ[4][HIDDEN];
    __shared__ unsigned short sK[4][HIDDEN];
    __shared__ unsigned short sV[4][HIDDEN];
    __shared__ float sA[4][64];

    const int t = threadIdx.x, lane = t & 63, wave = t >> 6;
    const int token = blockIdx.x * 4 + wave;
    const size_t base = (size_t)token * HIDDEN;
    const unsigned short* q = QKV + base;
    const unsigned short* k = QKV + (size_t)NTOK * HIDDEN + base;
    const unsigned short* v = QKV + 2 * (size_t)NTOK * HIDDEN + base;

#pragma unroll
    for (int i = 0; i < 2; ++i) {
        const int off = (i * 64 + lane) * 8;
        *(u16x8*)&sQ[wave][off] = *(const u16x8*)&q[off];
        *(u16x8*)&sK[wave][off] = *(const u16x8*)&k[off];
        *(u16x8*)&sV[wave][off] = *(const u16x8*)&v[off];
    }
    __syncthreads();

    const int h = lane >> 3, g = lane & 7;
    float sc = 0.f;
    const unsigned short* Qr = &sQ[wave][h * 128];
    const unsigned short* Kr = &sK[wave][g * 128];
#pragma unroll
    for (int d = 0; d < 128; d += 8) {
        u16x8 qv = *(const u16x8*)&Qr[d];
        u16x8 kv = *(const u16x8*)&Kr[d];
#pragma unroll
        for (int j = 0; j < 8; ++j) sc += b2f(qv[j]) * b2f(kv[j]);
    }
    sc *= -0.08838834764831845f;   // NEGATED scale, faithful to source quirk

    float mx = sc;
#pragma unroll
    for (int o = 1; o < 8; o <<= 1) mx = fmaxf(mx, __shfl_xor(mx, o, 64));
    const float e = __expf(sc - mx);
    float sm = e;
#pragma unroll
    for (int o = 1; o < 8; o <<= 1) sm += __shfl_xor(sm, o, 64);
    sA[wave][lane] = e / sm;
    __syncthreads();

    const int c = lane & 7;        // 16-wide d-chunk within head
    float ov[16];
#pragma unroll
    for (int j = 0; j < 16; ++j) ov[j] = 0.f;
    const float* Ar = &sA[wave][h * 8];
#pragma unroll
    for (int gg = 0; gg < 8; ++gg) {
        const float a = Ar[gg];
        const unsigned short* Vr = &sV[wave][gg * 128 + c * 16];
#pragma unroll
        for (int j = 0; j < 16; ++j) ov[j] += a * b2f(Vr[j]);
    }
    float* op = out + base + lane * 16;   // lane*16 == h*128 + c*16
#pragma unroll
    for (int j = 0; j < 16; j += 4) {
        float4 r = make_float4(ov[j], ov[j + 1], ov[j + 2], ov[j + 3]);
        *(float4*)&op[j] = r;
    }
}

extern "C" void kernel_launch(void* const* d_in, const int* in_sizes, int n_in,
                              void* d_out, int out_size, void* d_ws, size_t ws_size,
                              hipStream_t stream) {
    const float* x1 = (const float*)d_in[0];
    const float* Wq = (const float*)d_in[1];
    const float* bq = (const float*)d_in[2];
    const float* Wk = (const float*)d_in[3];
    const float* bk = (const float*)d_in[4];
    const float* Wv = (const float*)d_in[5];
    const float* bv = (const float*)d_in[6];
    float* out = (float*)d_out;

    // workspace layout (bf16 as ushort): Xb | Wb(q,k,v) | QKV  -> 140.5 MB
    unsigned short* Xb  = (unsigned short*)d_ws;
    unsigned short* Wb  = Xb + (size_t)NTOK * HIDDEN;
    unsigned short* QKV = Wb + 3 * (size_t)HIDDEN * HIDDEN;

    cvt_all<<<2048, 256, 0, stream>>>((const float4*)x1, (const float4*)Wq,
                                      (const float4*)Wk, (const float4*)Wv,
                                      (u16x4*)Xb);

    qkv_gemm<<<dim3(1536), 256, 0, stream>>>(Xb, Wb, bq, bk, bv, QKV);

    attn_k<<<NTOK / 4, 256, 0, stream>>>(QKV, out);
}